// Round 7
// baseline (232.530 us; speedup 1.0000x reference)
//
#include <hip/hip_runtime.h>
#include <hip/hip_bf16.h>

// StructureBuilder: masked patch-correlation attention. FP32 I/O, f16 internal.
//   prep:     conv1x1+inorm+relu -> q_act/k_act f16 images; q_act pre-scaled by
//             log2(e) so attn softmax runs in exp2 domain; vbar = tap-mean of V
//   build_kp: materialize K patch bank, row stride 144 (pad-free)
//   attn:     flash attention, key-split x2, swapped QK^T (S^T), in-lane softmax
//             (vote-gated deferred max, per-lane partial sums), in-register P
//             repack via cvt_pkrtz + ds_bpermute. V B-fragments loaded DIRECTLY
//             from global (vb is L2-hot) -- no Vt LDS round-trip. Bk
//             double-buffered via global_load_lds. XCD-aware block swizzle:
//             head = bid&7 so each XCD's L2 holds exactly one head's kp slice.
//             NOTE: accO rescale needs alpha of query quad*4+r via __shfl
//             (accO row = query, but m/l state lives in lane l15 = query).
//   combine:  flash-merge halves (exp2 domain) + head-mean -> att
//   out:      Wo conv + inorm + relu -> fp32

#define LL 4096          // H*W
#define CC 64            // channels
#define AA 128           // attention channels
#define NH_ 8            // heads
#define KSTR 144         // kp row stride (f16): 144 data, no pad; 18 x 8 halves
#define LOG2E 1.44269504088896340736f

typedef _Float16 half8 __attribute__((ext_vector_type(8)));
typedef float floatx4 __attribute__((ext_vector_type(4)));
typedef int intx4 __attribute__((ext_vector_type(4)));

__device__ __forceinline__ float fexp2(float x) {
    float r;
    asm("v_exp_f32 %0, %1" : "=v"(r) : "v"(x));
    return r;
}

// ---------------- K1: conv1x1 + inorm + relu -> activation images; vbar ----------------
__global__ __launch_bounds__(256) void prep_kernel(
    const float* __restrict__ feat,
    const float* __restrict__ masks,
    const float* __restrict__ Wq, const float* __restrict__ bq,
    const float* __restrict__ Wk, const float* __restrict__ bk,
    _Float16* __restrict__ q_act, _Float16* __restrict__ k_act,
    _Float16* __restrict__ vb)
{
    const int tid = threadIdx.x;
    const int b = blockIdx.x;
    __shared__ float sW[CC];
    __shared__ float sm[8];

    if (b >= 2 * AA) {
        // vbar[c][l] = (1/9) sum_taps f_unmasked[c, l + shift_t]  (OOB = 0)
        int c = b - 2 * AA;
        for (int p = 0; p < 16; ++p) {
            int l = p * 256 + tid;
            int y = l >> 6, x = l & 63;
            float s = 0.f;
            for (int ty = 0; ty < 3; ++ty) {
                int yy = y + 2 * (ty - 1);
                if (yy < 0 || yy > 63) continue;
                for (int tx = 0; tx < 3; ++tx) {
                    int xx = x + 2 * (tx - 1);
                    if (xx < 0 || xx > 63) continue;
                    int ll = yy * 64 + xx;
                    float hole = masks[ll] > 0.5f ? 1.f : 0.f;
                    s += feat[c * LL + ll] * (1.f - hole);
                }
            }
            vb[c * LL + l] = (_Float16)(s * (1.f / 9.f));
        }
        return;
    }

    const int a = b & (AA - 1);
    const int sel = b >> 7;  // 0 = q (hole pixels), 1 = k (unmasked pixels)
    const float* Wrow = (sel ? Wk : Wq) + a * CC;
    const float bias = sel ? bk[a] : bq[a];
    if (tid < CC) sW[tid] = Wrow[tid];
    __syncthreads();

    // conv: c-outer, pixel-inner (1 LDS read per 16 FMAs, 16-wide load ILP)
    float acc[16];
#pragma unroll
    for (int p = 0; p < 16; ++p) acc[p] = 0.f;
    for (int c = 0; c < CC; ++c) {
        float wc = sW[c];
        const float* fr = feat + (size_t)c * LL + tid;
#pragma unroll
        for (int p = 0; p < 16; ++p) acc[p] += wc * fr[p * 256];
    }

    float vals[16];
    float s1 = 0.f, s2 = 0.f;
#pragma unroll
    for (int p = 0; p < 16; ++p) {
        int l = p * 256 + tid;
        float hole = masks[l] > 0.5f ? 1.f : 0.f;
        float mf = sel ? (1.f - hole) : hole;
        float v = acc[p] * mf + bias;
        vals[p] = v; s1 += v; s2 += v * v;
    }
    for (int off = 32; off; off >>= 1) {
        s1 += __shfl_down(s1, off, 64);
        s2 += __shfl_down(s2, off, 64);
    }
    int wv = tid >> 6, ln = tid & 63;
    if (ln == 0) { sm[wv * 2] = s1; sm[wv * 2 + 1] = s2; }
    __syncthreads();
    s1 = sm[0] + sm[2] + sm[4] + sm[6];
    s2 = sm[1] + sm[3] + sm[5] + sm[7];
    float mu = s1 * (1.f / LL);
    float inv = rsqrtf(s2 * (1.f / LL) - mu * mu + 1e-5f);

    // q gets log2(e) folded in so attn softmax can use raw v_exp_f32 (exp2)
    const float oscale = sel ? 1.f : LOG2E;
    _Float16* act = (sel ? k_act : q_act) + (size_t)a * LL;
#pragma unroll
    for (int p = 0; p < 16; ++p) {
        int l = p * 256 + tid;
        float v = (vals[p] - mu) * inv;
        act[l] = (_Float16)(v > 0.f ? v * oscale : 0.f);
    }
}

// ---------------- K2: materialize K patch bank kp[n][l][KSTR] ----------------
// grid (8 heads, 64 image rows); tile = 64 pixels x 18 half8 chunks = 1152 chunks
__global__ __launch_bounds__(256) void build_kp(
    const _Float16* __restrict__ k_act, _Float16* __restrict__ kp)
{
    const int n = blockIdx.x, y = blockIdx.y;
    const int tid = threadIdx.x;
    const _Float16* ka = k_act + (size_t)n * 16 * LL;
    _Float16* base = kp + ((size_t)n * LL + y * 64) * KSTR;
#pragma unroll
    for (int i = 0; i < 5; ++i) {
        int idx = tid + i * 256;          // half8 chunk index within tile
        if (idx < 64 * 18) {
            int x = idx / 18, c18 = idx - x * 18;
            half8 v8;
#pragma unroll
            for (int j = 0; j < 8; ++j) {
                int d = c18 * 8 + j;      // always < 144
                int ah = d / 9, t = d - ah * 9;
                int ty = t / 3, tx = t - ty * 3;
                int yy = y + 2 * (ty - 1);
                int xx = x + 2 * (tx - 1);
                _Float16 v = (_Float16)0.f;
                if (yy >= 0 && yy <= 63 && xx >= 0 && xx <= 63)
                    v = ka[ah * LL + yy * 64 + xx];
                v8[j] = v;
            }
            *(half8*)(base + (size_t)idx * 8) = v8;   // rows exactly 18 chunks
        }
    }
}

// ---------------- K3: flash attention, key-split x2, swapped QK^T ----------------
// 512 blocks, 1D, XCD-swizzled: n = bid&7 (one head per XCD -> kp slice L2-fits),
// slot = bid>>3: qt2 = slot&31, h = slot>>5. 256 threads (4 waves), wave w =
// x-block covering BOTH image rows 2qt, 2qt+1 (shared K B-fragments).
// S^T layout: lane(quad,l15) holds S[key = nt*16+quad*4+r][query = w*16+l15].
// V B-fragments are loaded straight from global vb (L2-hot) -- no Vt LDS.
__global__ __launch_bounds__(256, 2) void attn_kernel(
    const _Float16* __restrict__ q_act, const _Float16* __restrict__ kp,
    const _Float16* __restrict__ vb,
    _Float16* __restrict__ Opart, float* __restrict__ ml)
{
    const int bid = blockIdx.x;
    const int n = bid & 7;            // XCD-aligned head
    const int slot = bid >> 3;
    const int qt2 = slot & 31;
    const int h = slot >> 5;
    const int jt0 = h * 32;
    const int tid = threadIdx.x;
    const int w = tid >> 6, lane = tid & 63;
    const int l15 = lane & 15, quad = lane >> 4;

    __shared__ __align__(16) _Float16 Bk[2][64 * KSTR + 16]; // 2 x 18,464 B

    // zero the Bk tail pads once (ks=4 tail of the last key row reads them;
    // must be finite: NaN * 0 would poison the MFMA accumulator)
    if (tid < 32) Bk[tid >> 4][64 * KSTR + (tid & 15)] = (_Float16)0.f;

    const _Float16* kpn = kp + (size_t)n * LL * KSTR;

    // async DMA: key tile jt -> dst. 18 chunks of 1024B; wave w takes w, w+4, ...
    auto issue_bk = [&](int jt, _Float16* dst) {
        const char* tile = (const char*)(kpn + (size_t)jt * 64 * KSTR) + (lane << 4);
        for (int c = w; c < 18; c += 4) {
            __builtin_amdgcn_global_load_lds(
                (const __attribute__((address_space(1))) void*)(tile + c * 1024),
                (__attribute__((address_space(3))) void*)(dst + c * 512),
                16, 0, 0);
        }
    };

    // Q B-fragments, both row-sets: query (y = 2*qt2+rs, x = w*16+l15),
    // d-slice = ks*32 + quad*8 + j, zero-padded for d >= 144
    half8 afrag[2][5];
    {
        const _Float16* qa = q_act + (size_t)n * 16 * LL;
        const int x = w * 16 + l15;
#pragma unroll
        for (int rs = 0; rs < 2; ++rs) {
            const int y = qt2 * 2 + rs;
#pragma unroll
            for (int ks = 0; ks < 5; ++ks) {
#pragma unroll
                for (int j = 0; j < 8; ++j) {
                    int d = ks * 32 + quad * 8 + j;
                    _Float16 v = (_Float16)0.f;
                    if (d < 144) {
                        int ah = d / 9, t = d - ah * 9;
                        int ty = t / 3, tx = t - ty * 3;
                        int yy = y + 2 * (ty - 1);
                        int xx = x + 2 * (tx - 1);
                        if (yy >= 0 && yy <= 63 && xx >= 0 && xx <= 63)
                            v = qa[ah * LL + yy * 64 + xx];
                    }
                    afrag[rs][ks][j] = v;
                }
            }
        }
    }

    floatx4 accO[2][4];
    float mrow[2], lrow[2];
#pragma unroll
    for (int rs = 0; rs < 2; ++rs) {
        mrow[rs] = -1e30f; lrow[rs] = 0.f;
#pragma unroll
        for (int i = 0; i < 4; ++i) accO[rs][i] = (floatx4){0.f, 0.f, 0.f, 0.f};
    }

    // bpermute source addresses for the P repack (bytes = lane*4)
    const int aLo = (((quad & 1) << 5) + l15) << 2;  // lane (quad&1)*2*16 + l15
    const int aHi = aLo + 64;                        // +16 lanes
    const bool selHi = (quad >> 1) != 0;

    // per-lane V base: V B-frag (nt,ks2) = vb[(nt*16+l15)*LL + jt*64 + (ks2*4+quad)*8]
    const _Float16* vpl = vb + (size_t)l15 * LL + quad * 8;

    issue_bk(jt0, Bk[0]);                            // async, in flight

    int cur = 0;
    for (int it = 0; it < 32; ++it) {
        __syncthreads();  // drains vmcnt: Bk[cur] DMA (in flight since last iter)

        // refill: issue NEXT K-tile DMA into the other buffer
        if (it < 31) issue_bk(jt0 + it + 1, Bk[cur ^ 1]);

        // V B-fragments for current tile, straight from global (L2-hot);
        // consumed at PV ~1200 cycles later -> latency hidden under QK^T.
        const _Float16* vp = vpl + (jt0 + it) * 64;
        half8 vfrag[4][2];
#pragma unroll
        for (int nt = 0; nt < 4; ++nt)
#pragma unroll
            for (int ks2 = 0; ks2 < 2; ++ks2)
                vfrag[nt][ks2] = *(const half8*)(vp + (size_t)nt * 16 * LL + ks2 * 32);

        const _Float16* bk = Bk[cur];

        // S^T tiles: mfma(A = K-frag, B = Q-frag). One K B-fragment read feeds
        // both row-sets. K = 160 with zero tail on the Q side.
        floatx4 accS[2][4];
#pragma unroll
        for (int rs = 0; rs < 2; ++rs)
#pragma unroll
            for (int i = 0; i < 4; ++i) accS[rs][i] = (floatx4){0.f, 0.f, 0.f, 0.f};
        __builtin_amdgcn_s_setprio(1);
        for (int ks = 0; ks < 5; ++ks) {
#pragma unroll
            for (int nt = 0; nt < 4; ++nt) {
                half8 bfr = *(const half8*)(bk + (nt * 16 + l15) * KSTR + ks * 32 + quad * 8);
                accS[0][nt] = __builtin_amdgcn_mfma_f32_16x16x32_f16(bfr, afrag[0][ks], accS[0][nt], 0, 0, 0);
                accS[1][nt] = __builtin_amdgcn_mfma_f32_16x16x32_f16(bfr, afrag[1][ks], accS[1][nt], 0, 0, 0);
            }
        }
        __builtin_amdgcn_s_setprio(0);

        // softmax (log2 domain) + in-register P repack, per row-set.
        // Lane owns query w*16+l15; its 16 accS values are keys nt*16+quad*4+r.
        half8 pfr[2][2];
#pragma unroll
        for (int rs = 0; rs < 2; ++rs) {
            // in-lane max of 16
            float t0 = fmaxf(fmaxf(accS[rs][0][0], accS[rs][0][1]), fmaxf(accS[rs][0][2], accS[rs][0][3]));
            float t1 = fmaxf(fmaxf(accS[rs][1][0], accS[rs][1][1]), fmaxf(accS[rs][1][2], accS[rs][1][3]));
            float t2 = fmaxf(fmaxf(accS[rs][2][0], accS[rs][2][1]), fmaxf(accS[rs][2][2], accS[rs][2][3]));
            float t3 = fmaxf(fmaxf(accS[rs][3][0], accS[rs][3][1]), fmaxf(accS[rs][3][2], accS[rs][3][3]));
            float tm = fmaxf(fmaxf(t0, t1), fmaxf(t2, t3));
            // vote-gated deferred max: P bounded by 2^3 = 8, fine in f32 accum
            if (!__all(tm <= mrow[rs] + 3.0f)) {
                tm = fmaxf(tm, __shfl_xor(tm, 16, 64));
                tm = fmaxf(tm, __shfl_xor(tm, 32, 64));
                float mn = fmaxf(mrow[rs], tm);
                float alpha = fexp2(mrow[rs] - mn);
                mrow[rs] = mn;
                lrow[rs] *= alpha;
                // accO row = QUERY quad*4+r (col = channel l15); its alpha
                // lives in lane l15 = quad*4+r -> fetch per-row via shuffle
                float af[4];
#pragma unroll
                for (int r = 0; r < 4; ++r) af[r] = __shfl(alpha, quad * 4 + r, 16);
#pragma unroll
                for (int nt = 0; nt < 4; ++nt)
#pragma unroll
                    for (int r = 0; r < 4; ++r) accO[rs][nt][r] *= af[r];
            }
            // exp + per-lane partial sum (cross-quad reduce deferred to epilogue)
            float rsum = 0.f;
#pragma unroll
            for (int nt = 0; nt < 4; ++nt)
#pragma unroll
                for (int r = 0; r < 4; ++r) {
                    float pv = fexp2(accS[rs][nt][r] - mrow[rs]);
                    accS[rs][nt][r] = pv;
                    rsum += pv;
                }
            lrow[rs] += rsum;

            // pack P pairs: word (nt,rp) = f16x2 of keys nt*16+quad*4+2rp, +1
            int pkw[4][2];
#pragma unroll
            for (int nt = 0; nt < 4; ++nt)
#pragma unroll
                for (int rp = 0; rp < 2; ++rp) {
                    auto hp = __builtin_amdgcn_cvt_pkrtz(accS[rs][nt][2 * rp],
                                                         accS[rs][nt][2 * rp + 1]);
                    pkw[nt][rp] = __builtin_bit_cast(int, hp);
                }
            // PV A-frag (ks2): word jw needs keys ks2*32+quad*8+2jw,+1 held by
            // lane quad_h=(quad&1)*2+(jw>>1) at word (nt=ks2*2+(quad>>1), jw&1)
#pragma unroll
            for (int ks2 = 0; ks2 < 2; ++ks2) {
                int w0A = __builtin_amdgcn_ds_bpermute(aLo, pkw[2 * ks2][0]);
                int w0B = __builtin_amdgcn_ds_bpermute(aLo, pkw[2 * ks2 + 1][0]);
                int w1A = __builtin_amdgcn_ds_bpermute(aLo, pkw[2 * ks2][1]);
                int w1B = __builtin_amdgcn_ds_bpermute(aLo, pkw[2 * ks2 + 1][1]);
                int w2A = __builtin_amdgcn_ds_bpermute(aHi, pkw[2 * ks2][0]);
                int w2B = __builtin_amdgcn_ds_bpermute(aHi, pkw[2 * ks2 + 1][0]);
                int w3A = __builtin_amdgcn_ds_bpermute(aHi, pkw[2 * ks2][1]);
                int w3B = __builtin_amdgcn_ds_bpermute(aHi, pkw[2 * ks2 + 1][1]);
                intx4 wvv;
                wvv[0] = selHi ? w0B : w0A;
                wvv[1] = selHi ? w1B : w1A;
                wvv[2] = selHi ? w2B : w2A;
                wvv[3] = selHi ? w3B : w3A;
                pfr[rs][ks2] = __builtin_bit_cast(half8, wvv);
            }
        }

        // O += P @ V^T: A = P-frag (regs), B = V-frag (regs, from global)
        __builtin_amdgcn_s_setprio(1);
#pragma unroll
        for (int ks2 = 0; ks2 < 2; ++ks2) {
#pragma unroll
            for (int nt = 0; nt < 4; ++nt) {
                accO[0][nt] = __builtin_amdgcn_mfma_f32_16x16x32_f16(pfr[0][ks2], vfrag[nt][ks2], accO[0][nt], 0, 0, 0);
                accO[1][nt] = __builtin_amdgcn_mfma_f32_16x16x32_f16(pfr[1][ks2], vfrag[nt][ks2], accO[1][nt], 0, 0, 0);
            }
        }
        __builtin_amdgcn_s_setprio(0);

        cur ^= 1;
    }

    // epilogue: cross-quad l reduction, normalize, store
#pragma unroll
    for (int rs = 0; rs < 2; ++rs) {
        const int y = qt2 * 2 + rs;
        float rsum = lrow[rs];
        rsum += __shfl_xor(rsum, 16, 64);
        rsum += __shfl_xor(rsum, 32, 64);
        float invl = 1.f / rsum;
        float iv[4];
#pragma unroll
        for (int r = 0; r < 4; ++r) iv[r] = __shfl(invl, quad * 4 + r, 16);

        _Float16* op = Opart + ((size_t)(n * 2 + h) * LL + y * 64 + w * 16) * CC;
#pragma unroll
        for (int r = 0; r < 4; ++r)
#pragma unroll
            for (int nt = 0; nt < 4; ++nt)
                op[(quad * 4 + r) * CC + nt * 16 + l15] = (_Float16)(accO[rs][nt][r] * iv[r]);

        if (quad == 0) {
            float* mlp = ml + ((size_t)n * LL + y * 64 + w * 16 + l15) * 4;
            mlp[2 * h] = mrow[rs];     // log2-domain reference max
            mlp[2 * h + 1] = rsum;
        }
    }
}

// ---------------- K4: flash-merge halves (exp2 domain) + head-mean ----------------
__global__ __launch_bounds__(256) void combine_kernel(
    const _Float16* __restrict__ Opart, const float* __restrict__ ml,
    float* __restrict__ att)
{
    int t = blockIdx.x * 256 + threadIdx.x;   // 0 .. LL*CC-1
    int l = t >> 6, c = t & 63;
    float s = 0.f;
#pragma unroll
    for (int n = 0; n < NH_; ++n) {
        const float* mlp = ml + ((size_t)n * LL + l) * 4;
        float m0 = mlp[0], l0 = mlp[1], m1 = mlp[2], l1 = mlp[3];
        float M = fmaxf(m0, m1);
        float w0 = l0 * fexp2(m0 - M);
        float w1 = l1 * fexp2(m1 - M);
        float o0 = (float)Opart[((size_t)(2 * n) * LL + l) * CC + c];
        float o1 = (float)Opart[((size_t)(2 * n + 1) * LL + l) * CC + c];
        s += (w0 * o0 + w1 * o1) / (w0 + w1);
    }
    att[t] = s * 0.125f;
}

// ---------------- K5: Wo conv + inorm + relu ----------------
__global__ __launch_bounds__(256) void out_kernel(
    const float* __restrict__ att,
    const float* __restrict__ Wo, const float* __restrict__ bo,
    float* __restrict__ out)
{
    const int o = blockIdx.x;
    const int tid = threadIdx.x;
    __shared__ float sW[CC];
    __shared__ float sm[8];
    if (tid < CC) sW[tid] = Wo[o * CC + tid];
    __syncthreads();
    const float bias = bo[o];

    float vals[16], s1 = 0.f, s2 = 0.f;
    for (int p = 0; p < 16; ++p) {
        int l = p * 256 + tid;
        const float4* arow = (const float4*)(att + (size_t)l * CC);
        float acc = bias;
#pragma unroll
        for (int c4 = 0; c4 < 16; ++c4) {
            float4 a4 = arow[c4];
            acc += sW[c4 * 4] * a4.x + sW[c4 * 4 + 1] * a4.y +
                   sW[c4 * 4 + 2] * a4.z + sW[c4 * 4 + 3] * a4.w;
        }
        vals[p] = acc; s1 += acc; s2 += acc * acc;
    }
    for (int off = 32; off; off >>= 1) {
        s1 += __shfl_down(s1, off, 64);
        s2 += __shfl_down(s2, off, 64);
    }
    int wv = tid >> 6, ln = tid & 63;
    if (ln == 0) { sm[wv * 2] = s1; sm[wv * 2 + 1] = s2; }
    __syncthreads();
    s1 = sm[0] + sm[2] + sm[4] + sm[6];
    s2 = sm[1] + sm[3] + sm[5] + sm[7];
    float mu = s1 * (1.f / LL);
    float inv = rsqrtf(s2 * (1.f / LL) - mu * mu + 1e-5f);
    for (int p = 0; p < 16; ++p) {
        int l = p * 256 + tid;
        float v = (vals[p] - mu) * inv;
        out[(size_t)o * LL + l] = v > 0.f ? v : 0.f;
    }
}

extern "C" void kernel_launch(void* const* d_in, const int* in_sizes, int n_in,
                              void* d_out, int out_size, void* d_ws, size_t ws_size,
                              hipStream_t stream) {
    const float* feat  = (const float*)d_in[0];
    const float* masks = (const float*)d_in[1];
    const float* Wq    = (const float*)d_in[2];
    const float* bq    = (const float*)d_in[3];
    const float* Wk    = (const float*)d_in[4];
    const float* bk    = (const float*)d_in[5];
    const float* Wo    = (const float*)d_in[6];
    const float* bo    = (const float*)d_in[7];
    float* out = (float*)d_out;

    char* ws = (char*)d_ws;
    // layout (bytes) — total 22,020,096 (~21 MB):
    //   q_act f16 [128][4096]       @ 0          (1,048,576)
    //   k_act f16 [128][4096]       @ 1,048,576  (1,048,576)
    //   vb    f16 [64][4096]        @ 2,097,152  (  524,288)
    //   att   f32 [4096][64]        @ 2,621,440  (1,048,576)
    //   kp    f16 [8][4096][144]    @ 3,670,016  (9,437,184)
    //   Opart f16 [16][4096][64]    @ 13,107,200 (8,388,608)
    //   ml    f32 [8][4096][4]      @ 21,495,808 (  524,288)
    _Float16* q_act = (_Float16*)ws;
    _Float16* k_act = (_Float16*)(ws + 1048576);
    _Float16* vb    = (_Float16*)(ws + 2097152);
    float*    att   = (float*)(ws + 2621440);
    _Float16* kp    = (_Float16*)(ws + 3670016);
    _Float16* Opart = (_Float16*)(ws + 13107200);
    float*    ml    = (float*)(ws + 21495808);

    prep_kernel<<<2 * AA + CC, 256, 0, stream>>>(feat, masks, Wq, bq, Wk, bk,
                                                 q_act, k_act, vb);
    dim3 gb(NH_, 64);
    build_kp<<<gb, 256, 0, stream>>>(k_act, kp);
    attn_kernel<<<512, 256, 0, stream>>>(q_act, kp, vb, Opart, ml);
    combine_kernel<<<LL * CC / 256, 256, 0, stream>>>(Opart, ml, att);
    out_kernel<<<CC, 256, 0, stream>>>(att, Wo, bo, out);
}

// Round 8
// 226.293 us; speedup vs baseline: 1.0276x; 1.0276x over previous
//
#include <hip/hip_runtime.h>
#include <hip/hip_bf16.h>

// StructureBuilder: masked patch-correlation attention. FP32 I/O, f16 internal.
//   prep:     conv1x1+inorm+relu -> q_act/k_act f16 images; q_act pre-scaled by
//             log2(e) so attn softmax runs in exp2 domain; vbar = tap-mean of V.
//             512 threads / 8 px per thread: ~10 waves/CU to hide L2 latency.
//   build_kp: materialize K patch bank, row stride 144. Source window staged in
//             LDS (16ah x 3rows x 68px) so the per-tap gather is LDS-local;
//             global reads and writes both coalesced.
//   attn:     flash attention, key-split x2, swapped QK^T (S^T), in-lane softmax
//             (vote-gated deferred max, per-lane partial sums), in-register P
//             repack via cvt_pkrtz + ds_bpermute. V B-fragments loaded DIRECTLY
//             from global (vb is L2-hot) -- no Vt LDS round-trip. Bk
//             double-buffered via global_load_lds. XCD-aware block swizzle:
//             head = bid&7 so each XCD's L2 holds exactly one head's kp slice.
//             NOTE: accO rescale needs alpha of query quad*4+r via __shfl
//             (accO row = query, but m/l state lives in lane l15 = query).
//   combine:  flash-merge halves (exp2 domain) + head-mean -> att
//   out:      Wo conv + inorm + relu -> fp32

#define LL 4096          // H*W
#define CC 64            // channels
#define AA 128           // attention channels
#define NH_ 8            // heads
#define KSTR 144         // kp row stride (f16): 144 data, no pad; 18 x 8 halves
#define LOG2E 1.44269504088896340736f

typedef _Float16 half8 __attribute__((ext_vector_type(8)));
typedef float floatx4 __attribute__((ext_vector_type(4)));
typedef int intx4 __attribute__((ext_vector_type(4)));

__device__ __forceinline__ float fexp2(float x) {
    float r;
    asm("v_exp_f32 %0, %1" : "=v"(r) : "v"(x));
    return r;
}

// ---------------- K1: conv1x1 + inorm + relu -> activation images; vbar ----------------
// 512 threads, 8 px/thread (was 256x16): doubles waves/CU for latency hiding.
__global__ __launch_bounds__(512) void prep_kernel(
    const float* __restrict__ feat,
    const float* __restrict__ masks,
    const float* __restrict__ Wq, const float* __restrict__ bq,
    const float* __restrict__ Wk, const float* __restrict__ bk,
    _Float16* __restrict__ q_act, _Float16* __restrict__ k_act,
    _Float16* __restrict__ vb)
{
    const int tid = threadIdx.x;
    const int b = blockIdx.x;
    __shared__ float sW[CC];
    __shared__ float sm[16];

    if (b >= 2 * AA) {
        // vbar[c][l] = (1/9) sum_taps f_unmasked[c, l + shift_t]  (OOB = 0)
        int c = b - 2 * AA;
        for (int p = 0; p < 8; ++p) {
            int l = p * 512 + tid;
            int y = l >> 6, x = l & 63;
            float s = 0.f;
            for (int ty = 0; ty < 3; ++ty) {
                int yy = y + 2 * (ty - 1);
                if (yy < 0 || yy > 63) continue;
                for (int tx = 0; tx < 3; ++tx) {
                    int xx = x + 2 * (tx - 1);
                    if (xx < 0 || xx > 63) continue;
                    int ll = yy * 64 + xx;
                    float hole = masks[ll] > 0.5f ? 1.f : 0.f;
                    s += feat[c * LL + ll] * (1.f - hole);
                }
            }
            vb[c * LL + l] = (_Float16)(s * (1.f / 9.f));
        }
        return;
    }

    const int a = b & (AA - 1);
    const int sel = b >> 7;  // 0 = q (hole pixels), 1 = k (unmasked pixels)
    const float* Wrow = (sel ? Wk : Wq) + a * CC;
    const float bias = sel ? bk[a] : bq[a];
    if (tid < CC) sW[tid] = Wrow[tid];
    __syncthreads();

    // conv: c-outer, pixel-inner (1 LDS read per 8 FMAs, 8-wide load ILP)
    float acc[8];
#pragma unroll
    for (int p = 0; p < 8; ++p) acc[p] = 0.f;
    for (int c = 0; c < CC; ++c) {
        float wc = sW[c];
        const float* fr = feat + (size_t)c * LL + tid;
#pragma unroll
        for (int p = 0; p < 8; ++p) acc[p] += wc * fr[p * 512];
    }

    float vals[8];
    float s1 = 0.f, s2 = 0.f;
#pragma unroll
    for (int p = 0; p < 8; ++p) {
        int l = p * 512 + tid;
        float hole = masks[l] > 0.5f ? 1.f : 0.f;
        float mf = sel ? (1.f - hole) : hole;
        float v = acc[p] * mf + bias;
        vals[p] = v; s1 += v; s2 += v * v;
    }
    for (int off = 32; off; off >>= 1) {
        s1 += __shfl_down(s1, off, 64);
        s2 += __shfl_down(s2, off, 64);
    }
    int wv = tid >> 6, ln = tid & 63;
    if (ln == 0) { sm[wv * 2] = s1; sm[wv * 2 + 1] = s2; }
    __syncthreads();
    s1 = 0.f; s2 = 0.f;
#pragma unroll
    for (int i = 0; i < 8; ++i) { s1 += sm[2 * i]; s2 += sm[2 * i + 1]; }
    float mu = s1 * (1.f / LL);
    float inv = rsqrtf(s2 * (1.f / LL) - mu * mu + 1e-5f);

    // q gets log2(e) folded in so attn softmax can use raw v_exp_f32 (exp2)
    const float oscale = sel ? 1.f : LOG2E;
    _Float16* act = (sel ? k_act : q_act) + (size_t)a * LL;
#pragma unroll
    for (int p = 0; p < 8; ++p) {
        int l = p * 512 + tid;
        float v = (vals[p] - mu) * inv;
        act[l] = (_Float16)(v > 0.f ? v * oscale : 0.f);
    }
}

// ---------------- K2: materialize K patch bank kp[n][l][KSTR] ----------------
// grid (8 heads, 64 image rows). Source window (16 ah x 3 rows x 68 px, border
// zero-filled) staged in LDS with coalesced global reads; the per-tap gather
// then hits LDS. Writes coalesced half8, rows exactly 18 chunks.
__global__ __launch_bounds__(256) void build_kp(
    const _Float16* __restrict__ k_act, _Float16* __restrict__ kp)
{
    const int n = blockIdx.x, y = blockIdx.y;
    const int tid = threadIdx.x;
    const _Float16* ka = k_act + (size_t)n * 16 * LL;
    __shared__ _Float16 kt[16][3][72];   // [ah][ty][xx+2], 68 used, pad to 72

    // stage: 48 rows (ah,ty) x 68 xr; consecutive tid -> consecutive xx (coalesced)
    for (int idx = tid; idx < 16 * 3 * 68; idx += 256) {
        int row = idx / 68, xr = idx - row * 68;    // xr = xx + 2
        int ah = row / 3, ty = row - ah * 3;
        int yy = y + 2 * (ty - 1);
        int xx = xr - 2;
        _Float16 v = (_Float16)0.f;
        if (yy >= 0 && yy <= 63 && xx >= 0 && xx <= 63)
            v = ka[ah * LL + yy * 64 + xx];
        kt[ah][ty][xr] = v;
    }
    __syncthreads();

    _Float16* base = kp + ((size_t)n * LL + y * 64) * KSTR;
#pragma unroll
    for (int i = 0; i < 5; ++i) {
        int idx = tid + i * 256;          // half8 chunk index within tile
        if (idx < 64 * 18) {
            int x = idx / 18, c18 = idx - x * 18;
            half8 v8;
#pragma unroll
            for (int j = 0; j < 8; ++j) {
                int d = c18 * 8 + j;      // always < 144
                int ah = d / 9, t = d - ah * 9;
                int ty = t / 3, tx = t - ty * 3;
                v8[j] = kt[ah][ty][x + 2 * tx];   // xx+2 = x + 2(tx-1) + 2
            }
            *(half8*)(base + (size_t)idx * 8) = v8;   // rows exactly 18 chunks
        }
    }
}

// ---------------- K3: flash attention, key-split x2, swapped QK^T ----------------
// 512 blocks, 1D, XCD-swizzled: n = bid&7 (one head per XCD -> kp slice L2-fits),
// slot = bid>>3: qt2 = slot&31, h = slot>>5. 256 threads (4 waves), wave w =
// x-block covering BOTH image rows 2qt, 2qt+1 (shared K B-fragments).
// S^T layout: lane(quad,l15) holds S[key = nt*16+quad*4+r][query = w*16+l15].
// V B-fragments are loaded straight from global vb (L2-hot) -- no Vt LDS.
__global__ __launch_bounds__(256, 2) void attn_kernel(
    const _Float16* __restrict__ q_act, const _Float16* __restrict__ kp,
    const _Float16* __restrict__ vb,
    _Float16* __restrict__ Opart, float* __restrict__ ml)
{
    const int bid = blockIdx.x;
    const int n = bid & 7;            // XCD-aligned head
    const int slot = bid >> 3;
    const int qt2 = slot & 31;
    const int h = slot >> 5;
    const int jt0 = h * 32;
    const int tid = threadIdx.x;
    const int w = tid >> 6, lane = tid & 63;
    const int l15 = lane & 15, quad = lane >> 4;

    __shared__ __align__(16) _Float16 Bk[2][64 * KSTR + 16]; // 2 x 18,464 B

    // zero the Bk tail pads once (ks=4 tail of the last key row reads them;
    // must be finite: NaN * 0 would poison the MFMA accumulator)
    if (tid < 32) Bk[tid >> 4][64 * KSTR + (tid & 15)] = (_Float16)0.f;

    const _Float16* kpn = kp + (size_t)n * LL * KSTR;

    // async DMA: key tile jt -> dst. 18 chunks of 1024B; wave w takes w, w+4, ...
    auto issue_bk = [&](int jt, _Float16* dst) {
        const char* tile = (const char*)(kpn + (size_t)jt * 64 * KSTR) + (lane << 4);
        for (int c = w; c < 18; c += 4) {
            __builtin_amdgcn_global_load_lds(
                (const __attribute__((address_space(1))) void*)(tile + c * 1024),
                (__attribute__((address_space(3))) void*)(dst + c * 512),
                16, 0, 0);
        }
    };

    // Q B-fragments, both row-sets: query (y = 2*qt2+rs, x = w*16+l15),
    // d-slice = ks*32 + quad*8 + j, zero-padded for d >= 144
    half8 afrag[2][5];
    {
        const _Float16* qa = q_act + (size_t)n * 16 * LL;
        const int x = w * 16 + l15;
#pragma unroll
        for (int rs = 0; rs < 2; ++rs) {
            const int y = qt2 * 2 + rs;
#pragma unroll
            for (int ks = 0; ks < 5; ++ks) {
#pragma unroll
                for (int j = 0; j < 8; ++j) {
                    int d = ks * 32 + quad * 8 + j;
                    _Float16 v = (_Float16)0.f;
                    if (d < 144) {
                        int ah = d / 9, t = d - ah * 9;
                        int ty = t / 3, tx = t - ty * 3;
                        int yy = y + 2 * (ty - 1);
                        int xx = x + 2 * (tx - 1);
                        if (yy >= 0 && yy <= 63 && xx >= 0 && xx <= 63)
                            v = qa[ah * LL + yy * 64 + xx];
                    }
                    afrag[rs][ks][j] = v;
                }
            }
        }
    }

    floatx4 accO[2][4];
    float mrow[2], lrow[2];
#pragma unroll
    for (int rs = 0; rs < 2; ++rs) {
        mrow[rs] = -1e30f; lrow[rs] = 0.f;
#pragma unroll
        for (int i = 0; i < 4; ++i) accO[rs][i] = (floatx4){0.f, 0.f, 0.f, 0.f};
    }

    // bpermute source addresses for the P repack (bytes = lane*4)
    const int aLo = (((quad & 1) << 5) + l15) << 2;  // lane (quad&1)*2*16 + l15
    const int aHi = aLo + 64;                        // +16 lanes
    const bool selHi = (quad >> 1) != 0;

    // per-lane V base: V B-frag (nt,ks2) = vb[(nt*16+l15)*LL + jt*64 + (ks2*4+quad)*8]
    const _Float16* vpl = vb + (size_t)l15 * LL + quad * 8;

    issue_bk(jt0, Bk[0]);                            // async, in flight

    int cur = 0;
    for (int it = 0; it < 32; ++it) {
        __syncthreads();  // drains vmcnt: Bk[cur] DMA (in flight since last iter)

        // refill: issue NEXT K-tile DMA into the other buffer
        if (it < 31) issue_bk(jt0 + it + 1, Bk[cur ^ 1]);

        // V B-fragments for current tile, straight from global (L2-hot);
        // consumed at PV ~1200 cycles later -> latency hidden under QK^T.
        const _Float16* vp = vpl + (jt0 + it) * 64;
        half8 vfrag[4][2];
#pragma unroll
        for (int nt = 0; nt < 4; ++nt)
#pragma unroll
            for (int ks2 = 0; ks2 < 2; ++ks2)
                vfrag[nt][ks2] = *(const half8*)(vp + (size_t)nt * 16 * LL + ks2 * 32);

        const _Float16* bk = Bk[cur];

        // S^T tiles: mfma(A = K-frag, B = Q-frag). One K B-fragment read feeds
        // both row-sets. K = 160 with zero tail on the Q side.
        floatx4 accS[2][4];
#pragma unroll
        for (int rs = 0; rs < 2; ++rs)
#pragma unroll
            for (int i = 0; i < 4; ++i) accS[rs][i] = (floatx4){0.f, 0.f, 0.f, 0.f};
        __builtin_amdgcn_s_setprio(1);
        for (int ks = 0; ks < 5; ++ks) {
#pragma unroll
            for (int nt = 0; nt < 4; ++nt) {
                half8 bfr = *(const half8*)(bk + (nt * 16 + l15) * KSTR + ks * 32 + quad * 8);
                accS[0][nt] = __builtin_amdgcn_mfma_f32_16x16x32_f16(bfr, afrag[0][ks], accS[0][nt], 0, 0, 0);
                accS[1][nt] = __builtin_amdgcn_mfma_f32_16x16x32_f16(bfr, afrag[1][ks], accS[1][nt], 0, 0, 0);
            }
        }
        __builtin_amdgcn_s_setprio(0);

        // softmax (log2 domain) + in-register P repack, per row-set.
        // Lane owns query w*16+l15; its 16 accS values are keys nt*16+quad*4+r.
        half8 pfr[2][2];
#pragma unroll
        for (int rs = 0; rs < 2; ++rs) {
            // in-lane max of 16
            float t0 = fmaxf(fmaxf(accS[rs][0][0], accS[rs][0][1]), fmaxf(accS[rs][0][2], accS[rs][0][3]));
            float t1 = fmaxf(fmaxf(accS[rs][1][0], accS[rs][1][1]), fmaxf(accS[rs][1][2], accS[rs][1][3]));
            float t2 = fmaxf(fmaxf(accS[rs][2][0], accS[rs][2][1]), fmaxf(accS[rs][2][2], accS[rs][2][3]));
            float t3 = fmaxf(fmaxf(accS[rs][3][0], accS[rs][3][1]), fmaxf(accS[rs][3][2], accS[rs][3][3]));
            float tm = fmaxf(fmaxf(t0, t1), fmaxf(t2, t3));
            // vote-gated deferred max: P bounded by 2^3 = 8, fine in f32 accum
            if (!__all(tm <= mrow[rs] + 3.0f)) {
                tm = fmaxf(tm, __shfl_xor(tm, 16, 64));
                tm = fmaxf(tm, __shfl_xor(tm, 32, 64));
                float mn = fmaxf(mrow[rs], tm);
                float alpha = fexp2(mrow[rs] - mn);
                mrow[rs] = mn;
                lrow[rs] *= alpha;
                // accO row = QUERY quad*4+r (col = channel l15); its alpha
                // lives in lane l15 = quad*4+r -> fetch per-row via shuffle
                float af[4];
#pragma unroll
                for (int r = 0; r < 4; ++r) af[r] = __shfl(alpha, quad * 4 + r, 16);
#pragma unroll
                for (int nt = 0; nt < 4; ++nt)
#pragma unroll
                    for (int r = 0; r < 4; ++r) accO[rs][nt][r] *= af[r];
            }
            // exp + per-lane partial sum (cross-quad reduce deferred to epilogue)
            float rsum = 0.f;
#pragma unroll
            for (int nt = 0; nt < 4; ++nt)
#pragma unroll
                for (int r = 0; r < 4; ++r) {
                    float pv = fexp2(accS[rs][nt][r] - mrow[rs]);
                    accS[rs][nt][r] = pv;
                    rsum += pv;
                }
            lrow[rs] += rsum;

            // pack P pairs: word (nt,rp) = f16x2 of keys nt*16+quad*4+2rp, +1
            int pkw[4][2];
#pragma unroll
            for (int nt = 0; nt < 4; ++nt)
#pragma unroll
                for (int rp = 0; rp < 2; ++rp) {
                    auto hp = __builtin_amdgcn_cvt_pkrtz(accS[rs][nt][2 * rp],
                                                         accS[rs][nt][2 * rp + 1]);
                    pkw[nt][rp] = __builtin_bit_cast(int, hp);
                }
            // PV A-frag (ks2): word jw needs keys ks2*32+quad*8+2jw,+1 held by
            // lane quad_h=(quad&1)*2+(jw>>1) at word (nt=ks2*2+(quad>>1), jw&1)
#pragma unroll
            for (int ks2 = 0; ks2 < 2; ++ks2) {
                int w0A = __builtin_amdgcn_ds_bpermute(aLo, pkw[2 * ks2][0]);
                int w0B = __builtin_amdgcn_ds_bpermute(aLo, pkw[2 * ks2 + 1][0]);
                int w1A = __builtin_amdgcn_ds_bpermute(aLo, pkw[2 * ks2][1]);
                int w1B = __builtin_amdgcn_ds_bpermute(aLo, pkw[2 * ks2 + 1][1]);
                int w2A = __builtin_amdgcn_ds_bpermute(aHi, pkw[2 * ks2][0]);
                int w2B = __builtin_amdgcn_ds_bpermute(aHi, pkw[2 * ks2 + 1][0]);
                int w3A = __builtin_amdgcn_ds_bpermute(aHi, pkw[2 * ks2][1]);
                int w3B = __builtin_amdgcn_ds_bpermute(aHi, pkw[2 * ks2 + 1][1]);
                intx4 wvv;
                wvv[0] = selHi ? w0B : w0A;
                wvv[1] = selHi ? w1B : w1A;
                wvv[2] = selHi ? w2B : w2A;
                wvv[3] = selHi ? w3B : w3A;
                pfr[rs][ks2] = __builtin_bit_cast(half8, wvv);
            }
        }

        // O += P @ V^T: A = P-frag (regs), B = V-frag (regs, from global)
        __builtin_amdgcn_s_setprio(1);
#pragma unroll
        for (int ks2 = 0; ks2 < 2; ++ks2) {
#pragma unroll
            for (int nt = 0; nt < 4; ++nt) {
                accO[0][nt] = __builtin_amdgcn_mfma_f32_16x16x32_f16(pfr[0][ks2], vfrag[nt][ks2], accO[0][nt], 0, 0, 0);
                accO[1][nt] = __builtin_amdgcn_mfma_f32_16x16x32_f16(pfr[1][ks2], vfrag[nt][ks2], accO[1][nt], 0, 0, 0);
            }
        }
        __builtin_amdgcn_s_setprio(0);

        cur ^= 1;
    }

    // epilogue: cross-quad l reduction, normalize, store
#pragma unroll
    for (int rs = 0; rs < 2; ++rs) {
        const int y = qt2 * 2 + rs;
        float rsum = lrow[rs];
        rsum += __shfl_xor(rsum, 16, 64);
        rsum += __shfl_xor(rsum, 32, 64);
        float invl = 1.f / rsum;
        float iv[4];
#pragma unroll
        for (int r = 0; r < 4; ++r) iv[r] = __shfl(invl, quad * 4 + r, 16);

        _Float16* op = Opart + ((size_t)(n * 2 + h) * LL + y * 64 + w * 16) * CC;
#pragma unroll
        for (int r = 0; r < 4; ++r)
#pragma unroll
            for (int nt = 0; nt < 4; ++nt)
                op[(quad * 4 + r) * CC + nt * 16 + l15] = (_Float16)(accO[rs][nt][r] * iv[r]);

        if (quad == 0) {
            float* mlp = ml + ((size_t)n * LL + y * 64 + w * 16 + l15) * 4;
            mlp[2 * h] = mrow[rs];     // log2-domain reference max
            mlp[2 * h + 1] = rsum;
        }
    }
}

// ---------------- K4: flash-merge halves (exp2 domain) + head-mean ----------------
__global__ __launch_bounds__(256) void combine_kernel(
    const _Float16* __restrict__ Opart, const float* __restrict__ ml,
    float* __restrict__ att)
{
    int t = blockIdx.x * 256 + threadIdx.x;   // 0 .. LL*CC-1
    int l = t >> 6, c = t & 63;
    float s = 0.f;
#pragma unroll
    for (int n = 0; n < NH_; ++n) {
        const float* mlp = ml + ((size_t)n * LL + l) * 4;
        float m0 = mlp[0], l0 = mlp[1], m1 = mlp[2], l1 = mlp[3];
        float M = fmaxf(m0, m1);
        float w0 = l0 * fexp2(m0 - M);
        float w1 = l1 * fexp2(m1 - M);
        float o0 = (float)Opart[((size_t)(2 * n) * LL + l) * CC + c];
        float o1 = (float)Opart[((size_t)(2 * n + 1) * LL + l) * CC + c];
        s += (w0 * o0 + w1 * o1) / (w0 + w1);
    }
    att[t] = s * 0.125f;
}

// ---------------- K5: Wo conv + inorm + relu ----------------
__global__ __launch_bounds__(256) void out_kernel(
    const float* __restrict__ att,
    const float* __restrict__ Wo, const float* __restrict__ bo,
    float* __restrict__ out)
{
    const int o = blockIdx.x;
    const int tid = threadIdx.x;
    __shared__ float sW[CC];
    __shared__ float sm[8];
    if (tid < CC) sW[tid] = Wo[o * CC + tid];
    __syncthreads();
    const float bias = bo[o];

    float vals[16], s1 = 0.f, s2 = 0.f;
    for (int p = 0; p < 16; ++p) {
        int l = p * 256 + tid;
        const float4* arow = (const float4*)(att + (size_t)l * CC);
        float acc = bias;
#pragma unroll
        for (int c4 = 0; c4 < 16; ++c4) {
            float4 a4 = arow[c4];
            acc += sW[c4 * 4] * a4.x + sW[c4 * 4 + 1] * a4.y +
                   sW[c4 * 4 + 2] * a4.z + sW[c4 * 4 + 3] * a4.w;
        }
        vals[p] = acc; s1 += acc; s2 += acc * acc;
    }
    for (int off = 32; off; off >>= 1) {
        s1 += __shfl_down(s1, off, 64);
        s2 += __shfl_down(s2, off, 64);
    }
    int wv = tid >> 6, ln = tid & 63;
    if (ln == 0) { sm[wv * 2] = s1; sm[wv * 2 + 1] = s2; }
    __syncthreads();
    s1 = sm[0] + sm[2] + sm[4] + sm[6];
    s2 = sm[1] + sm[3] + sm[5] + sm[7];
    float mu = s1 * (1.f / LL);
    float inv = rsqrtf(s2 * (1.f / LL) - mu * mu + 1e-5f);
    for (int p = 0; p < 16; ++p) {
        int l = p * 256 + tid;
        float v = (vals[p] - mu) * inv;
        out[(size_t)o * LL + l] = v > 0.f ? v : 0.f;
    }
}

extern "C" void kernel_launch(void* const* d_in, const int* in_sizes, int n_in,
                              void* d_out, int out_size, void* d_ws, size_t ws_size,
                              hipStream_t stream) {
    const float* feat  = (const float*)d_in[0];
    const float* masks = (const float*)d_in[1];
    const float* Wq    = (const float*)d_in[2];
    const float* bq    = (const float*)d_in[3];
    const float* Wk    = (const float*)d_in[4];
    const float* bk    = (const float*)d_in[5];
    const float* Wo    = (const float*)d_in[6];
    const float* bo    = (const float*)d_in[7];
    float* out = (float*)d_out;

    char* ws = (char*)d_ws;
    // layout (bytes) — total 22,020,096 (~21 MB):
    //   q_act f16 [128][4096]       @ 0          (1,048,576)
    //   k_act f16 [128][4096]       @ 1,048,576  (1,048,576)
    //   vb    f16 [64][4096]        @ 2,097,152  (  524,288)
    //   att   f32 [4096][64]        @ 2,621,440  (1,048,576)
    //   kp    f16 [8][4096][144]    @ 3,670,016  (9,437,184)
    //   Opart f16 [16][4096][64]    @ 13,107,200 (8,388,608)
    //   ml    f32 [8][4096][4]      @ 21,495,808 (  524,288)
    _Float16* q_act = (_Float16*)ws;
    _Float16* k_act = (_Float16*)(ws + 1048576);
    _Float16* vb    = (_Float16*)(ws + 2097152);
    float*    att   = (float*)(ws + 2621440);
    _Float16* kp    = (_Float16*)(ws + 3670016);
    _Float16* Opart = (_Float16*)(ws + 13107200);
    float*    ml    = (float*)(ws + 21495808);

    prep_kernel<<<2 * AA + CC, 512, 0, stream>>>(feat, masks, Wq, bq, Wk, bk,
                                                 q_act, k_act, vb);
    dim3 gb(NH_, 64);
    build_kp<<<gb, 256, 0, stream>>>(k_act, kp);
    attn_kernel<<<512, 256, 0, stream>>>(q_act, kp, vb, Opart, ml);
    combine_kernel<<<LL * CC / 256, 256, 0, stream>>>(Opart, ml, att);
    out_kernel<<<CC, 256, 0, stream>>>(att, Wo, bo, out);
}